// Round 1
// baseline (1202.216 us; speedup 1.0000x reference)
//
#include <hip/hip_runtime.h>
#include <hip/hip_bf16.h>

// Problem constants (fixed by reference): B=4, L=4096, H=16, Dh=Dv=128, CHUNK=1024
#define BATCH 4
#define SEQL  4096
#define NH    16
#define DH    128
#define CHUNK 1024
#define NCHUNK 4
#define BQ 64      // q rows per block
#define KB 32      // kv tile

typedef __bf16 bf16x8 __attribute__((ext_vector_type(8)));
typedef float  f32x4  __attribute__((ext_vector_type(4)));
typedef unsigned short ushort8 __attribute__((ext_vector_type(8)));

static __device__ inline __bf16 to_bf16(float f) {
    __hip_bfloat16 h = __float2bfloat16(f);
    return *reinterpret_cast<__bf16*>(&h);
}

// ---------------- RoPE cos/sin table: tbl[l][j] = (cos,sin)((l+start)*freq_j), 4096x64 float2 = 2MB
__global__ __launch_bounds__(256) void rope_tbl_kernel(float2* __restrict__ tbl,
                                                       const int* __restrict__ start_p) {
    int i = blockIdx.x * 256 + threadIdx.x;   // over SEQL*64
    int l = i >> 6, j = i & 63;
    // freq = exp(-j * ln(10000)/64)
    float freq = expf(-0.14391156831212787f * (float)j);
    float t = (float)(l + *start_p) * freq;
    tbl[i] = make_float2(cosf(t), sinf(t));
}

// ---------------- Flash attention over one 64-row Q block of one (b, chunk, head)
__global__ __launch_bounds__(256) void attn_kernel(
    const float* __restrict__ qg, const float* __restrict__ kg,
    const float* __restrict__ vg, const float2* __restrict__ tbl,
    float* __restrict__ outg)
{
    __shared__ __hip_bfloat16 Klds[32][136];    // [key][d], +8 pad (row 272B)
    __shared__ __hip_bfloat16 Vlds[128][40];    // [dv][key], +8 pad (row 80B)
    __shared__ __hip_bfloat16 Plds[4][16][40];  // per-wave P, [row][key], +8 pad

    const int tid  = threadIdx.x;
    const int lane = tid & 63;
    const int w    = tid >> 6;      // wave 0..3
    const int ln15 = lane & 15;
    const int g    = lane >> 4;     // 0..3

    const int bid = blockIdx.x;
    const int qbi = bid & 15;
    const int h   = (bid >> 4) & 15;
    const int n   = (bid >> 8) & 3;
    const int b   = bid >> 10;
    const int qb  = qbi * BQ;

    // ---- Q fragments with RoPE (A-frag: row = ln15, d = ks*32 + 8*g + j) ----
    const int qpos = n * CHUNK + qb + w * 16 + ln15;
    const float* qrow = qg + (((size_t)(b * SEQL + qpos)) * NH + h) * DH;
    const float2* tq = tbl + (size_t)qpos * 64;

    float xq[4][8];
    #pragma unroll
    for (int ks = 0; ks < 4; ++ks) {
        const float* p = qrow + ks * 32 + 8 * g;
        float4 a = *(const float4*)p;
        float4 c = *(const float4*)(p + 4);
        xq[ks][0] = a.x; xq[ks][1] = a.y; xq[ks][2] = a.z; xq[ks][3] = a.w;
        xq[ks][4] = c.x; xq[ks][5] = c.y; xq[ks][6] = c.z; xq[ks][7] = c.w;
    }
    float csx[2][8], csy[2][8];
    #pragma unroll
    for (int hh = 0; hh < 2; ++hh)
        #pragma unroll
        for (int j = 0; j < 8; ++j) {
            float2 c = tq[hh * 32 + 8 * g + j];
            csx[hh][j] = c.x; csy[hh][j] = c.y;
        }
    bf16x8 qf[4];
    #pragma unroll
    for (int ks = 0; ks < 4; ++ks)
        #pragma unroll
        for (int j = 0; j < 8; ++j) {
            float c = csx[ks & 1][j], s = csy[ks & 1][j];
            float val = (ks < 2) ? (xq[ks][j] * c - xq[ks + 2][j] * s)
                                 : (xq[ks][j] * c + xq[ks - 2][j] * s);
            qf[ks][j] = to_bf16(val * 0.08838834764831845f); // fold 1/sqrt(128)
        }

    // ---- running state ----
    f32x4 o[8];
    #pragma unroll
    for (int dt = 0; dt < 8; ++dt) o[dt] = (f32x4){0.f, 0.f, 0.f, 0.f};
    float mrun[4] = {-1e30f, -1e30f, -1e30f, -1e30f};
    float lrun[4] = {0.f, 0.f, 0.f, 0.f};

    const int nt = qb / 32 + 2;              // kv tiles needed for this block
    const int wave_max_row = qb + w * 16 + 15;

    for (int t = 0; t < nt; ++t) {
        // ---- stage K tile (rope + bf16), rows of 128 ----
        {
            int kr = tid >> 3;
            int d0 = (tid & 7) << 4;
            int kpos = n * CHUNK + t * KB + kr;
            const float* krow = kg + (((size_t)(b * SEQL + kpos)) * NH + h) * DH;
            const float2* tk = tbl + (size_t)kpos * 64;
            int j0 = d0 & 63;
            bool lo = d0 < 64;
            alignas(16) __hip_bfloat16 tmp[16];
            #pragma unroll
            for (int i4 = 0; i4 < 4; ++i4) {
                float4 x = *(const float4*)(krow + d0 + i4 * 4);
                float4 y = *(const float4*)(krow + (d0 ^ 64) + i4 * 4);
                float xx[4] = {x.x, x.y, x.z, x.w};
                float yy[4] = {y.x, y.y, y.z, y.w};
                #pragma unroll
                for (int j = 0; j < 4; ++j) {
                    float2 c = tk[j0 + i4 * 4 + j];
                    float r = lo ? (xx[j] * c.x - yy[j] * c.y)
                                 : (xx[j] * c.x + yy[j] * c.y);
                    tmp[i4 * 4 + j] = __float2bfloat16(r);
                }
            }
            *(ushort8*)&Klds[kr][d0]     = *(const ushort8*)&tmp[0];
            *(ushort8*)&Klds[kr][d0 + 8] = *(const ushort8*)&tmp[8];
        }
        // ---- stage V tile transposed: Vlds[dv][key] ----
        {
            int dv = tid & 127;
            int half = tid >> 7;
            const float* vcol = vg + (((size_t)(b * SEQL + n * CHUNK + t * KB + half * 16)) * NH + h) * DH + dv;
            alignas(16) __hip_bfloat16 tmp[16];
            #pragma unroll
            for (int i = 0; i < 16; ++i)
                tmp[i] = __float2bfloat16(vcol[(size_t)i * (NH * DH)]);
            *(ushort8*)&Vlds[dv][half * 16]     = *(const ushort8*)&tmp[0];
            *(ushort8*)&Vlds[dv][half * 16 + 8] = *(const ushort8*)&tmp[8];
        }
        __syncthreads();

        if (t * KB <= wave_max_row) {
            // ---- S = Q @ K^T : two 16x16 tiles (kt=0,1) ----
            f32x4 s0 = (f32x4){0.f, 0.f, 0.f, 0.f};
            f32x4 s1 = (f32x4){0.f, 0.f, 0.f, 0.f};
            #pragma unroll
            for (int ks = 0; ks < 4; ++ks) {
                bf16x8 b0 = *(const bf16x8*)&Klds[ln15][ks * 32 + 8 * g];
                bf16x8 b1 = *(const bf16x8*)&Klds[16 + ln15][ks * 32 + 8 * g];
                s0 = __builtin_amdgcn_mfma_f32_16x16x32_bf16(qf[ks], b0, s0, 0, 0, 0);
                s1 = __builtin_amdgcn_mfma_f32_16x16x32_bf16(qf[ks], b1, s1, 0, 0, 0);
            }
            // ---- causal mask + online softmax (C layout: col=ln15, row=g*4+r) ----
            const int key0  = t * KB + ln15;
            const int qrow0 = qb + w * 16 + g * 4;
            float alph[4];
            #pragma unroll
            for (int r = 0; r < 4; ++r) {
                int qr = qrow0 + r;
                float v0 = (key0      <= qr) ? s0[r] : -1e30f;
                float v1 = (key0 + 16 <= qr) ? s1[r] : -1e30f;
                float m = fmaxf(v0, v1);
                m = fmaxf(m, __shfl_xor(m, 1));
                m = fmaxf(m, __shfl_xor(m, 2));
                m = fmaxf(m, __shfl_xor(m, 4));
                m = fmaxf(m, __shfl_xor(m, 8));
                float mnew = fmaxf(mrun[r], m);
                float al = __expf(mrun[r] - mnew);
                mrun[r] = mnew;
                float p0 = __expf(v0 - mnew);
                float p1 = __expf(v1 - mnew);
                float rs = p0 + p1;
                rs += __shfl_xor(rs, 1);
                rs += __shfl_xor(rs, 2);
                rs += __shfl_xor(rs, 4);
                rs += __shfl_xor(rs, 8);
                lrun[r] = lrun[r] * al + rs;
                alph[r] = al;
                Plds[w][g * 4 + r][ln15]      = __float2bfloat16(p0);
                Plds[w][g * 4 + r][16 + ln15] = __float2bfloat16(p1);
            }
            asm volatile("" ::: "memory"); // order Plds writes before reads (per-wave LDS is in-order)
            #pragma unroll
            for (int dt = 0; dt < 8; ++dt)
                #pragma unroll
                for (int r = 0; r < 4; ++r) o[dt][r] *= alph[r];
            // ---- O += P @ V ----
            bf16x8 pa = *(const bf16x8*)&Plds[w][ln15][8 * g];
            #pragma unroll
            for (int dt = 0; dt < 8; ++dt) {
                bf16x8 bv = *(const bf16x8*)&Vlds[dt * 16 + ln15][8 * g];
                o[dt] = __builtin_amdgcn_mfma_f32_16x16x32_bf16(pa, bv, o[dt], 0, 0, 0);
            }
        }
        __syncthreads();
    }

    // ---- epilogue: normalize + store fp32 ----
    float linv[4];
    #pragma unroll
    for (int r = 0; r < 4; ++r) linv[r] = 1.0f / lrun[r];
    const int orow0 = n * CHUNK + qb + w * 16 + g * 4;
    #pragma unroll
    for (int dt = 0; dt < 8; ++dt)
        #pragma unroll
        for (int r = 0; r < 4; ++r) {
            size_t idx = ((size_t)(b * SEQL + orow0 + r)) * (NH * DH) + h * DH + dt * 16 + ln15;
            outg[idx] = o[dt][r] * linv[r];
        }
}

extern "C" void kernel_launch(void* const* d_in, const int* in_sizes, int n_in,
                              void* d_out, int out_size, void* d_ws, size_t ws_size,
                              hipStream_t stream) {
    const float* q = (const float*)d_in[0];
    const float* k = (const float*)d_in[1];
    const float* v = (const float*)d_in[2];
    const int* start_index = (const int*)d_in[3];
    float* out = (float*)d_out;
    float2* tbl = (float2*)d_ws;  // 4096*64*8B = 2MB

    rope_tbl_kernel<<<(SEQL * 64) / 256, 256, 0, stream>>>(tbl, start_index);
    attn_kernel<<<BATCH * NCHUNK * NH * (CHUNK / BQ), 256, 0, stream>>>(q, k, v, tbl, out);
}